// Round 2
// baseline (349.452 us; speedup 1.0000x reference)
//
#include <hip/hip_runtime.h>
#include <string.h>

typedef unsigned short u16;
typedef __bf16 bf16x8 __attribute__((ext_vector_type(8)));
typedef float floatx4 __attribute__((ext_vector_type(4)));

#define HEADS  16
#define DH     64
#define BATCH  2
#define NQ     512
#define NKV    4096
#define DMODEL 1024
#define INNER  1024
#define SCALE  0.125f

__device__ __forceinline__ u16 f2bf(float f) {
  union { float f; unsigned int u; } v; v.f = f;
  unsigned int u = v.u;
  unsigned int r = u + 0x7fffu + ((u >> 16) & 1u);   // RNE
  return (u16)(r >> 16);
}

// ---------------- fp32 -> bf16 convert, 8 elems/thread ----------------
__global__ __launch_bounds__(256) void conv_bf16(const float* __restrict__ x,
                                                 u16* __restrict__ y) {
  const size_t i = (size_t)blockIdx.x * 256 + threadIdx.x;
  const float4* p = (const float4*)x + i * 2;
  float4 a = p[0], b = p[1];
  union { u16 s[8]; uint4 q; } o;
  o.s[0] = f2bf(a.x); o.s[1] = f2bf(a.y); o.s[2] = f2bf(a.z); o.s[3] = f2bf(a.w);
  o.s[4] = f2bf(b.x); o.s[5] = f2bf(b.y); o.s[6] = f2bf(b.z); o.s[7] = f2bf(b.w);
  *(uint4*)(y + i * 8) = o.q;
}

// ---------------- transpose+convert: Wt[n][k] = bf16(W[k][n]), W is KxN ----
__global__ __launch_bounds__(256) void transpose_conv(const float* __restrict__ W,
                                                      u16* __restrict__ Wt,
                                                      int K, int N) {
  __shared__ float tile[32][33];
  const int tx = threadIdx.x & 31, ty = threadIdx.x >> 5;  // 32x8
  const int n0 = blockIdx.x * 32, k0 = blockIdx.y * 32;
  for (int i = 0; i < 32; i += 8)
    tile[ty + i][tx] = W[(size_t)(k0 + ty + i) * N + n0 + tx];
  __syncthreads();
  for (int i = 0; i < 32; i += 8)
    Wt[(size_t)(n0 + ty + i) * K + k0 + tx] = f2bf(tile[tx][ty + i]);
}

// ---------------- GEMM: C[MxN] = A[MxK](bf16) * Bt[NxK](bf16)^T ----------
// 128x128 tile, 256 threads = 4 waves, each wave 64x64 via 4x4 MFMA 16x16x32.
// LDS row stride 40 ushorts: 80B -> frag-read bank aliasing is 2-way (free).
#define LDK 40
template<bool OUT_BF16>
__global__ __launch_bounds__(256) void gemm_bt(const u16* __restrict__ A,
                                               const u16* __restrict__ Bt,
                                               float* __restrict__ Cf,
                                               u16* __restrict__ Cb,
                                               const float* __restrict__ bias,
                                               int M, int N, int K) {
  __shared__ u16 As[128 * LDK];
  __shared__ u16 Bs[128 * LDK];
  const int tid  = threadIdx.x;
  const int lane = tid & 63, wave = tid >> 6;
  const int wr = wave >> 1, wc = wave & 1;
  const int l16 = lane & 15, quad = lane >> 4;
  const int bm = blockIdx.y, bn = blockIdx.x;
  // staging: each thread loads 16 consecutive k at (row r0, col c0) in both tiles
  const int r0 = tid >> 1;
  const int c0 = (tid & 1) * 16;
  const size_t aBase = ((size_t)bm * 128 + r0) * K + c0;
  const size_t bBase = ((size_t)bn * 128 + r0) * K + c0;

  floatx4 acc[4][4] = {};
  for (int k0 = 0; k0 < K; k0 += 32) {
    const uint4* pa = (const uint4*)(A + aBase + k0);
    const uint4* pb = (const uint4*)(Bt + bBase + k0);
    uint4 va0 = pa[0], va1 = pa[1];
    uint4 vb0 = pb[0], vb1 = pb[1];
    *(uint4*)&As[r0 * LDK + c0]     = va0;
    *(uint4*)&As[r0 * LDK + c0 + 8] = va1;
    *(uint4*)&Bs[r0 * LDK + c0]     = vb0;
    *(uint4*)&Bs[r0 * LDK + c0 + 8] = vb1;
    __syncthreads();
    bf16x8 af[4], bfr[4];
#pragma unroll
    for (int i = 0; i < 4; ++i)
      af[i] = *(const bf16x8*)&As[(wr * 64 + i * 16 + l16) * LDK + quad * 8];
#pragma unroll
    for (int j = 0; j < 4; ++j)
      bfr[j] = *(const bf16x8*)&Bs[(wc * 64 + j * 16 + l16) * LDK + quad * 8];
#pragma unroll
    for (int i = 0; i < 4; ++i)
#pragma unroll
      for (int j = 0; j < 4; ++j)
        acc[i][j] = __builtin_amdgcn_mfma_f32_16x16x32_bf16(af[i], bfr[j], acc[i][j], 0, 0, 0);
    __syncthreads();
  }
  // epilogue: C/D layout col=lane&15, row=quad*4+reg  (verified m89/m91)
#pragma unroll
  for (int i = 0; i < 4; ++i) {
    const int rowb = bm * 128 + wr * 64 + i * 16 + quad * 4;
#pragma unroll
    for (int j = 0; j < 4; ++j) {
      const int col = bn * 128 + wc * 64 + j * 16 + l16;
#pragma unroll
      for (int r = 0; r < 4; ++r) {
        const size_t idx = (size_t)(rowb + r) * N + col;
        if (OUT_BF16) Cb[idx] = f2bf(acc[i][j][r]);
        else          Cf[idx] = acc[i][j][r] + bias[col];
      }
    }
  }
}

// ---------------- flash attention ----------------
// block = 256 thr = 4 waves; block handles (b,h,qtile of 64); wave owns 16 q rows.
// K-chunks of 64 keys; online softmax; P goes C-layout -> LDS -> A-layout.
__global__ __launch_bounds__(256) void attn_fused(const u16* __restrict__ Qh,
                                                  const u16* __restrict__ KVp,
                                                  const int* __restrict__ mask,
                                                  u16* __restrict__ Out) {
  __shared__ u16 Qs[64 * 72];
  __shared__ u16 Ks[64 * 72];
  __shared__ u16 Vs[64 * 72];   // transposed: Vs[d][key]
  __shared__ u16 Ps[4][16 * 72];
  __shared__ float Msk[64];
  const int tid = threadIdx.x;
  const int lane = tid & 63, w = tid >> 6;
  const int l16 = lane & 15, quad = lane >> 4;
  const int qt = blockIdx.x & 7;
  const int h  = (blockIdx.x >> 3) & 15;
  const int b  = blockIdx.x >> 7;
  const int rs = tid >> 2;            // staging row 0..63
  const int d0 = (tid & 3) * 16;      // staging col group

  { // stage Q tile (64 x 64)
    const uint4* p = (const uint4*)(Qh + ((size_t)(b * NQ + qt * 64 + rs)) * INNER + h * DH + d0);
    *(uint4*)&Qs[rs * 72 + d0]     = p[0];
    *(uint4*)&Qs[rs * 72 + d0 + 8] = p[1];
  }
  __syncthreads();
  bf16x8 aq[2];
  aq[0] = *(const bf16x8*)&Qs[(w * 16 + l16) * 72 + quad * 8];
  aq[1] = *(const bf16x8*)&Qs[(w * 16 + l16) * 72 + 32 + quad * 8];

  floatx4 o[4] = {};
  float m_r[4] = {-1e30f, -1e30f, -1e30f, -1e30f};
  float l_r[4] = {0.f, 0.f, 0.f, 0.f};

  for (int c = 0; c < NKV / 64; ++c) {
    const int key0 = c * 64;
    { // stage K chunk (rows) and V chunk (transposed) and mask
      const size_t kvrow = ((size_t)(b * NKV + key0 + rs)) * (2 * INNER) + h * DH;
      const uint4* pk = (const uint4*)(KVp + kvrow + d0);
      uint4 k0v = pk[0], k1v = pk[1];
      *(uint4*)&Ks[rs * 72 + d0]     = k0v;
      *(uint4*)&Ks[rs * 72 + d0 + 8] = k1v;
      const uint4* pv = (const uint4*)(KVp + kvrow + INNER + d0);
      union { uint4 q[2]; u16 s[16]; } vu;
      vu.q[0] = pv[0]; vu.q[1] = pv[1];
#pragma unroll
      for (int i = 0; i < 16; ++i) Vs[(d0 + i) * 72 + rs] = vu.s[i];
      // mask is numpy bool -> harness passes as int32 (one int per key)
      if (tid < 64) Msk[tid] = (mask[(size_t)b * NKV + key0 + tid] != 0) ? 0.0f : -1e30f;
    }
    __syncthreads();

    // S = Q K^T  (per wave: 16 q x 64 keys)
    float sv[4][4];
#pragma unroll
    for (int nt = 0; nt < 4; ++nt) {
      bf16x8 b0 = *(const bf16x8*)&Ks[(nt * 16 + l16) * 72 + quad * 8];
      bf16x8 b1 = *(const bf16x8*)&Ks[(nt * 16 + l16) * 72 + 32 + quad * 8];
      floatx4 t = {0.f, 0.f, 0.f, 0.f};
      t = __builtin_amdgcn_mfma_f32_16x16x32_bf16(aq[0], b0, t, 0, 0, 0);
      t = __builtin_amdgcn_mfma_f32_16x16x32_bf16(aq[1], b1, t, 0, 0, 0);
      const float mk = Msk[nt * 16 + l16];
#pragma unroll
      for (int r = 0; r < 4; ++r) sv[nt][r] = t[r] * SCALE + mk;
    }
    // row stats: row = quad*4 + r lives across the 16 lanes sharing a quad
    float mnew[4], alpha[4], psum[4];
#pragma unroll
    for (int r = 0; r < 4; ++r) {
      float t = fmaxf(fmaxf(sv[0][r], sv[1][r]), fmaxf(sv[2][r], sv[3][r]));
      t = fmaxf(t, __shfl_xor(t, 1));
      t = fmaxf(t, __shfl_xor(t, 2));
      t = fmaxf(t, __shfl_xor(t, 4));
      t = fmaxf(t, __shfl_xor(t, 8));
      mnew[r] = fmaxf(m_r[r], t);
      alpha[r] = __expf(m_r[r] - mnew[r]);
      m_r[r] = mnew[r];
      psum[r] = 0.f;
    }
    // P = exp(S - m), write to LDS (A-layout source), accumulate row sums
#pragma unroll
    for (int nt = 0; nt < 4; ++nt)
#pragma unroll
      for (int r = 0; r < 4; ++r) {
        float p = __expf(sv[nt][r] - mnew[r]);
        psum[r] += p;
        Ps[w][(quad * 4 + r) * 72 + nt * 16 + l16] = f2bf(p);
      }
#pragma unroll
    for (int r = 0; r < 4; ++r) {
      float t = psum[r];
      t += __shfl_xor(t, 1);
      t += __shfl_xor(t, 2);
      t += __shfl_xor(t, 4);
      t += __shfl_xor(t, 8);
      l_r[r] = l_r[r] * alpha[r] + t;
#pragma unroll
      for (int dt = 0; dt < 4; ++dt) o[dt][r] *= alpha[r];
    }
    // O += P V   (P from LDS in A-layout; V transposed in LDS)
    bf16x8 ap[2];
    ap[0] = *(const bf16x8*)&Ps[w][l16 * 72 + quad * 8];
    ap[1] = *(const bf16x8*)&Ps[w][l16 * 72 + 32 + quad * 8];
#pragma unroll
    for (int dt = 0; dt < 4; ++dt) {
      bf16x8 bv0 = *(const bf16x8*)&Vs[(dt * 16 + l16) * 72 + quad * 8];
      bf16x8 bv1 = *(const bf16x8*)&Vs[(dt * 16 + l16) * 72 + 32 + quad * 8];
      o[dt] = __builtin_amdgcn_mfma_f32_16x16x32_bf16(ap[0], bv0, o[dt], 0, 0, 0);
      o[dt] = __builtin_amdgcn_mfma_f32_16x16x32_bf16(ap[1], bv1, o[dt], 0, 0, 0);
    }
    __syncthreads();
  }
  // epilogue: normalize and store bf16
#pragma unroll
  for (int r = 0; r < 4; ++r) {
    const float inv = 1.0f / l_r[r];
    const size_t row = (size_t)(b * NQ + qt * 64 + w * 16 + quad * 4 + r);
#pragma unroll
    for (int dt = 0; dt < 4; ++dt)
      Out[row * INNER + h * DH + dt * 16 + l16] = f2bf(o[dt][r] * inv);
  }
}

// ---------------- launcher ----------------
extern "C" void kernel_launch(void* const* d_in, const int* in_sizes, int n_in,
                              void* d_out, int out_size, void* d_ws, size_t ws_size,
                              hipStream_t stream) {
  const float* q    = (const float*)d_in[0];
  const float* kv   = (const float*)d_in[1];
  const int*   mask = (const int*)d_in[2];   // numpy bool -> int32 per harness convention
  const float* Wq   = (const float*)d_in[3];
  const float* Wkv  = (const float*)d_in[4];
  const float* Wo   = (const float*)d_in[5];
  const float* bo   = (const float*)d_in[6];
  float* out = (float*)d_out;

  char* ws = (char*)d_ws;
  u16* qb   = (u16*)(ws);                       // 2*512*1024        = 1M elems
  u16* kvb  = (u16*)(ws + (2u << 20));          // 2*4096*1024       = 8M
  u16* Wqt  = (u16*)(ws + (18u << 20));         // 1024*1024
  u16* Wkvt = (u16*)(ws + (20u << 20));         // 2048*1024
  u16* Wot  = (u16*)(ws + (24u << 20));         // 1024*1024
  u16* qh   = (u16*)(ws + (26u << 20));         // 1024*1024
  u16* kvp  = (u16*)(ws + (28u << 20));         // 8192*2048
  u16* attn = (u16*)(ws + (60u << 20));         // 1024*1024
  // total ~62 MB of ws

  conv_bf16<<<dim3((BATCH * NQ * DMODEL) / 2048), 256, 0, stream>>>(q, qb);
  conv_bf16<<<dim3((BATCH * NKV * DMODEL) / 2048), 256, 0, stream>>>(kv, kvb);
  transpose_conv<<<dim3(INNER / 32, DMODEL / 32), 256, 0, stream>>>(Wq, Wqt, DMODEL, INNER);
  transpose_conv<<<dim3(2 * INNER / 32, DMODEL / 32), 256, 0, stream>>>(Wkv, Wkvt, DMODEL, 2 * INNER);
  transpose_conv<<<dim3(DMODEL / 32, INNER / 32), 256, 0, stream>>>(Wo, Wot, INNER, DMODEL);

  // qh = qb @ Wq   (1024x1024x1024)
  gemm_bt<true><<<dim3(INNER / 128, (BATCH * NQ) / 128), 256, 0, stream>>>(
      qb, Wqt, nullptr, qh, nullptr, BATCH * NQ, INNER, DMODEL);
  // kvp = kvb @ Wkv (8192x2048x1024)
  gemm_bt<true><<<dim3((2 * INNER) / 128, (BATCH * NKV) / 128), 256, 0, stream>>>(
      kvb, Wkvt, nullptr, kvp, nullptr, BATCH * NKV, 2 * INNER, DMODEL);
  // attention
  attn_fused<<<dim3(BATCH * HEADS * (NQ / 64)), 256, 0, stream>>>(qh, kvp, mask, attn);
  // out = attn @ Wo + bo (fp32)
  gemm_bt<false><<<dim3(DMODEL / 128, (BATCH * NQ) / 128), 256, 0, stream>>>(
      attn, Wot, out, nullptr, bo, BATCH * NQ, DMODEL, INNER);
}

// Round 3
// 274.610 us; speedup vs baseline: 1.2725x; 1.2725x over previous
//
#include <hip/hip_runtime.h>
#include <string.h>

typedef unsigned short u16;
typedef __bf16 bf16x8 __attribute__((ext_vector_type(8)));
typedef float floatx4 __attribute__((ext_vector_type(4)));

#define HEADS  16
#define DH     64
#define BATCH  2
#define NQ     512
#define NKV    4096
#define DMODEL 1024
#define INNER  1024
#define SCALE  0.125f
#define SPLIT  4          // KV partitions for flash-decoding
#define KEYS_PER_PART (NKV / SPLIT)

__device__ __forceinline__ u16 f2bf(float f) {
  union { float f; unsigned int u; } v; v.f = f;
  unsigned int u = v.u;
  unsigned int r = u + 0x7fffu + ((u >> 16) & 1u);   // RNE
  return (u16)(r >> 16);
}

// async global->LDS, 16B per lane; LDS dest = wave-uniform base + lane*16
__device__ __forceinline__ void gll16(const u16* g, u16* l) {
  __builtin_amdgcn_global_load_lds(
      (const __attribute__((address_space(1))) unsigned int*)g,
      (__attribute__((address_space(3))) unsigned int*)l, 16, 0, 0);
}

// ---------------- fp32 -> bf16 convert, 8 elems/thread ----------------
__global__ __launch_bounds__(256) void conv_bf16(const float* __restrict__ x,
                                                 u16* __restrict__ y) {
  const size_t i = (size_t)blockIdx.x * 256 + threadIdx.x;
  const float4* p = (const float4*)x + i * 2;
  float4 a = p[0], b = p[1];
  union { u16 s[8]; uint4 q; } o;
  o.s[0] = f2bf(a.x); o.s[1] = f2bf(a.y); o.s[2] = f2bf(a.z); o.s[3] = f2bf(a.w);
  o.s[4] = f2bf(b.x); o.s[5] = f2bf(b.y); o.s[6] = f2bf(b.z); o.s[7] = f2bf(b.w);
  *(uint4*)(y + i * 8) = o.q;
}

// ---------------- transpose+convert: Wt[n][k] = bf16(W[k][n]), W is KxN ----
__global__ __launch_bounds__(256) void transpose_conv(const float* __restrict__ W,
                                                      u16* __restrict__ Wt,
                                                      int K, int N) {
  __shared__ float tile[32][33];
  const int tx = threadIdx.x & 31, ty = threadIdx.x >> 5;  // 32x8
  const int n0 = blockIdx.x * 32, k0 = blockIdx.y * 32;
  for (int i = 0; i < 32; i += 8)
    tile[ty + i][tx] = W[(size_t)(k0 + ty + i) * N + n0 + tx];
  __syncthreads();
  for (int i = 0; i < 32; i += 8)
    Wt[(size_t)(n0 + ty + i) * K + k0 + tx] = f2bf(tile[tx][ty + i]);
}

// ---------------- GEMM: C[MxN] = A[MxK](bf16) * Bt[NxK](bf16)^T ----------
// m97 structure: 128x128 tile, BK=32, global_load_lds width 16 into unpadded
// LDS [128 rows][32 k]; XOR swizzle kb^= (row>>1)&3 applied on the GLOBAL
// source address so LDS frag reads stay bank-uniform.
template<bool OUT_BF16>
__global__ __launch_bounds__(256) void gemm_bt(const u16* __restrict__ A,
                                               const u16* __restrict__ Bt,
                                               float* __restrict__ Cf,
                                               u16* __restrict__ Cb,
                                               const float* __restrict__ bias,
                                               int M, int N, int K) {
  __shared__ __align__(16) u16 As[128 * 32];
  __shared__ __align__(16) u16 Bs[128 * 32];
  const int tid  = threadIdx.x;
  const int lane = tid & 63, wave = tid >> 6;
  const int wr = wave >> 1, wc = wave & 1;
  const int l16 = lane & 15, quad = lane >> 4;
  const int bm = blockIdx.y, bn = blockIdx.x;
  // staging: inst i covers LDS slots [i*256 + tid]; slot -> row = slot>>2, kb' = tid&3
  const int r0 = tid >> 2;                         // inst0 row; inst1 row = r0+64
  const int kb = (tid & 3) ^ ((tid >> 3) & 3);     // swizzled k-block (same for both insts)
  const u16* aP0 = A  + ((size_t)bm * 128 + r0)      * K + kb * 8;
  const u16* aP1 = A  + ((size_t)bm * 128 + r0 + 64) * K + kb * 8;
  const u16* bP0 = Bt + ((size_t)bn * 128 + r0)      * K + kb * 8;
  const u16* bP1 = Bt + ((size_t)bn * 128 + r0 + 64) * K + kb * 8;
  u16* ldsA0 = As + wave * 512;          // slots wave*64..: 64 lanes * 16B
  u16* ldsA1 = As + 2048 + wave * 512;
  u16* ldsB0 = Bs + wave * 512;
  u16* ldsB1 = Bs + 2048 + wave * 512;
  // fragment-read swizzle: k-block = quad ^ ((row>>1)&3); row=..+l16 -> (l16>>1)&3
  const int ko = ((quad ^ ((l16 >> 1) & 3)) << 3);

  floatx4 acc[4][4] = {};
  for (int k0 = 0; k0 < K; k0 += 32) {
    gll16(aP0 + k0, ldsA0);
    gll16(aP1 + k0, ldsA1);
    gll16(bP0 + k0, ldsB0);
    gll16(bP1 + k0, ldsB1);
    __syncthreads();
    bf16x8 af[4], bfr[4];
#pragma unroll
    for (int i = 0; i < 4; ++i)
      af[i] = *(const bf16x8*)&As[(wr * 64 + i * 16 + l16) * 32 + ko];
#pragma unroll
    for (int j = 0; j < 4; ++j)
      bfr[j] = *(const bf16x8*)&Bs[(wc * 64 + j * 16 + l16) * 32 + ko];
#pragma unroll
    for (int i = 0; i < 4; ++i)
#pragma unroll
      for (int j = 0; j < 4; ++j)
        acc[i][j] = __builtin_amdgcn_mfma_f32_16x16x32_bf16(af[i], bfr[j], acc[i][j], 0, 0, 0);
    __syncthreads();
  }
  // epilogue: C/D layout col=lane&15, row=quad*4+reg  (verified m89/m91)
#pragma unroll
  for (int i = 0; i < 4; ++i) {
    const int rowb = bm * 128 + wr * 64 + i * 16 + quad * 4;
#pragma unroll
    for (int j = 0; j < 4; ++j) {
      const int col = bn * 128 + wc * 64 + j * 16 + l16;
#pragma unroll
      for (int r = 0; r < 4; ++r) {
        const size_t idx = (size_t)(rowb + r) * N + col;
        if (OUT_BF16) Cb[idx] = f2bf(acc[i][j][r]);
        else          Cf[idx] = acc[i][j][r] + bias[col];
      }
    }
  }
}

// ---------------- flash attention, split-K partials ----------------
// grid = B*H*QT*SPLIT; block = 4 waves; each block: 64 q x KEYS_PER_PART keys.
// Outputs unnormalized O (fp32) + per-row (m,l) stats for the combine pass.
__global__ __launch_bounds__(256) void attn_part(const u16* __restrict__ Qh,
                                                 const u16* __restrict__ KVp,
                                                 const int* __restrict__ mask,
                                                 float* __restrict__ Opart,
                                                 float* __restrict__ Mst,
                                                 float* __restrict__ Lst) {
  __shared__ u16 Qs[64 * 72];
  __shared__ u16 Ks[64 * 72];
  __shared__ u16 Vs[64 * 72];   // transposed: Vs[d][key], key-block xor-swizzled
  __shared__ u16 Ps[4][16 * 72];
  __shared__ float Msk[64];
  const int tid = threadIdx.x;
  const int lane = tid & 63, w = tid >> 6;
  const int l16 = lane & 15, quad = lane >> 4;
  const int part = blockIdx.x & (SPLIT - 1);
  const int qt = (blockIdx.x >> 2) & 7;
  const int h  = (blockIdx.x >> 5) & 15;
  const int b  = blockIdx.x >> 9;
  const int rs = tid >> 2;            // staging row 0..63
  const int dq = tid & 3;             // d-group 0..3
  const int d0 = dq * 16;
  // V-transpose write: col = swizzled_block*8 + (rs&7); block' = (rs>>3) ^ (dq<<1)
  const int vcol = (((rs >> 3) ^ (dq << 1)) & 7) * 8 + (rs & 7);

  { // stage Q tile (64 x 64)
    const uint4* p = (const uint4*)(Qh + ((size_t)(b * NQ + qt * 64 + rs)) * INNER + h * DH + d0);
    *(uint4*)&Qs[rs * 72 + d0]     = p[0];
    *(uint4*)&Qs[rs * 72 + d0 + 8] = p[1];
  }
  __syncthreads();
  bf16x8 aq[2];
  aq[0] = *(const bf16x8*)&Qs[(w * 16 + l16) * 72 + quad * 8];
  aq[1] = *(const bf16x8*)&Qs[(w * 16 + l16) * 72 + 32 + quad * 8];

  floatx4 o[4] = {};
  float m_r[4] = {-1e30f, -1e30f, -1e30f, -1e30f};
  float l_r[4] = {0.f, 0.f, 0.f, 0.f};

  for (int c = 0; c < KEYS_PER_PART / 64; ++c) {
    const int key0 = part * KEYS_PER_PART + c * 64;
    { // stage K chunk (rows), V chunk (transposed+swizzled), mask
      const size_t kvrow = ((size_t)(b * NKV + key0 + rs)) * (2 * INNER) + h * DH;
      const uint4* pk = (const uint4*)(KVp + kvrow + d0);
      uint4 k0v = pk[0], k1v = pk[1];
      *(uint4*)&Ks[rs * 72 + d0]     = k0v;
      *(uint4*)&Ks[rs * 72 + d0 + 8] = k1v;
      const uint4* pv = (const uint4*)(KVp + kvrow + INNER + d0);
      union { uint4 q[2]; u16 s[16]; } vu;
      vu.q[0] = pv[0]; vu.q[1] = pv[1];
#pragma unroll
      for (int i = 0; i < 16; ++i) Vs[(d0 + i) * 72 + vcol] = vu.s[i];
      if (tid < 64) Msk[tid] = (mask[(size_t)b * NKV + key0 + tid] != 0) ? 0.0f : -1e30f;
    }
    __syncthreads();

    // S = Q K^T  (per wave: 16 q x 64 keys)
    float sv[4][4];
#pragma unroll
    for (int nt = 0; nt < 4; ++nt) {
      bf16x8 b0 = *(const bf16x8*)&Ks[(nt * 16 + l16) * 72 + quad * 8];
      bf16x8 b1 = *(const bf16x8*)&Ks[(nt * 16 + l16) * 72 + 32 + quad * 8];
      floatx4 t = {0.f, 0.f, 0.f, 0.f};
      t = __builtin_amdgcn_mfma_f32_16x16x32_bf16(aq[0], b0, t, 0, 0, 0);
      t = __builtin_amdgcn_mfma_f32_16x16x32_bf16(aq[1], b1, t, 0, 0, 0);
      const float mk = Msk[nt * 16 + l16];
#pragma unroll
      for (int r = 0; r < 4; ++r) sv[nt][r] = t[r] * SCALE + mk;
    }
    // row stats: row = quad*4 + r lives across the 16 lanes sharing a quad
    float mnew[4], alpha[4], psum[4];
#pragma unroll
    for (int r = 0; r < 4; ++r) {
      float t = fmaxf(fmaxf(sv[0][r], sv[1][r]), fmaxf(sv[2][r], sv[3][r]));
      t = fmaxf(t, __shfl_xor(t, 1));
      t = fmaxf(t, __shfl_xor(t, 2));
      t = fmaxf(t, __shfl_xor(t, 4));
      t = fmaxf(t, __shfl_xor(t, 8));
      mnew[r] = fmaxf(m_r[r], t);
      alpha[r] = __expf(m_r[r] - mnew[r]);
      m_r[r] = mnew[r];
      psum[r] = 0.f;
    }
    // P = exp(S - m) -> LDS (A-layout source), accumulate row sums
#pragma unroll
    for (int nt = 0; nt < 4; ++nt)
#pragma unroll
      for (int r = 0; r < 4; ++r) {
        float p = __expf(sv[nt][r] - mnew[r]);
        psum[r] += p;
        Ps[w][(quad * 4 + r) * 72 + nt * 16 + l16] = f2bf(p);
      }
#pragma unroll
    for (int r = 0; r < 4; ++r) {
      float t = psum[r];
      t += __shfl_xor(t, 1);
      t += __shfl_xor(t, 2);
      t += __shfl_xor(t, 4);
      t += __shfl_xor(t, 8);
      l_r[r] = l_r[r] * alpha[r] + t;
#pragma unroll
      for (int dt = 0; dt < 4; ++dt) o[dt][r] *= alpha[r];
    }
    // O += P V   (V swizzled: stored block = orig_block ^ (dt<<1))
    bf16x8 ap[2];
    ap[0] = *(const bf16x8*)&Ps[w][l16 * 72 + quad * 8];
    ap[1] = *(const bf16x8*)&Ps[w][l16 * 72 + 32 + quad * 8];
#pragma unroll
    for (int dt = 0; dt < 4; ++dt) {
      const int vb = ((quad ^ (dt << 1)) & 7) * 8;
      bf16x8 bv0 = *(const bf16x8*)&Vs[(dt * 16 + l16) * 72 + vb];
      bf16x8 bv1 = *(const bf16x8*)&Vs[(dt * 16 + l16) * 72 + (vb ^ 32)];
      o[dt] = __builtin_amdgcn_mfma_f32_16x16x32_bf16(ap[0], bv0, o[dt], 0, 0, 0);
      o[dt] = __builtin_amdgcn_mfma_f32_16x16x32_bf16(ap[1], bv1, o[dt], 0, 0, 0);
    }
    __syncthreads();
  }
  // epilogue: write unnormalized partial O (fp32) + stats
  const int pid = blockIdx.x;
#pragma unroll
  for (int r = 0; r < 4; ++r) {
    const int q = w * 16 + quad * 4 + r;
    if (l16 == 0) { Mst[pid * 64 + q] = m_r[r]; Lst[pid * 64 + q] = l_r[r]; }
#pragma unroll
    for (int dt = 0; dt < 4; ++dt)
      Opart[(size_t)pid * 4096 + q * 64 + dt * 16 + l16] = o[dt][r];
  }
}

// ---------------- combine split-K partials ----------------
// grid = 256 (one per b,h,qt tile); thread t: q = t>>2, d-block = (t&3)*16
__global__ __launch_bounds__(256) void attn_combine(const float* __restrict__ Opart,
                                                    const float* __restrict__ Mst,
                                                    const float* __restrict__ Lst,
                                                    u16* __restrict__ Out) {
  const int x = blockIdx.x;
  const int t = threadIdx.x;
  const int q = t >> 2, db = (t & 3) * 16;
  const int b = x >> 7, h = (x >> 3) & 15, qt = x & 7;
  float ms[SPLIT], ls[SPLIT];
#pragma unroll
  for (int s = 0; s < SPLIT; ++s) {
    ms[s] = Mst[(size_t)(x * SPLIT + s) * 64 + q];
    ls[s] = Lst[(size_t)(x * SPLIT + s) * 64 + q];
  }
  float M = fmaxf(fmaxf(ms[0], ms[1]), fmaxf(ms[2], ms[3]));
  float wgt[SPLIT], L = 0.f;
#pragma unroll
  for (int s = 0; s < SPLIT; ++s) { wgt[s] = __expf(ms[s] - M); L += wgt[s] * ls[s]; }
  const float inv = 1.0f / L;
  float acc[16] = {};
#pragma unroll
  for (int s = 0; s < SPLIT; ++s) {
    const float4* p = (const float4*)&Opart[(size_t)(x * SPLIT + s) * 4096 + q * 64 + db];
    const float ws = wgt[s];
#pragma unroll
    for (int i = 0; i < 4; ++i) {
      float4 v = p[i];
      acc[i * 4 + 0] += ws * v.x; acc[i * 4 + 1] += ws * v.y;
      acc[i * 4 + 2] += ws * v.z; acc[i * 4 + 3] += ws * v.w;
    }
  }
  union { u16 s[16]; uint4 v[2]; } ou;
#pragma unroll
  for (int i = 0; i < 16; ++i) ou.s[i] = f2bf(acc[i] * inv);
  u16* dst = Out + ((size_t)(b * NQ + qt * 64 + q)) * INNER + h * DH + db;
  *(uint4*)dst = ou.v[0]; *(uint4*)(dst + 8) = ou.v[1];
}

// ---------------- launcher ----------------
extern "C" void kernel_launch(void* const* d_in, const int* in_sizes, int n_in,
                              void* d_out, int out_size, void* d_ws, size_t ws_size,
                              hipStream_t stream) {
  const float* q    = (const float*)d_in[0];
  const float* kv   = (const float*)d_in[1];
  const int*   mask = (const int*)d_in[2];   // numpy bool -> int32 per harness convention
  const float* Wq   = (const float*)d_in[3];
  const float* Wkv  = (const float*)d_in[4];
  const float* Wo   = (const float*)d_in[5];
  const float* bo   = (const float*)d_in[6];
  float* out = (float*)d_out;

  char* ws = (char*)d_ws;
  // region [0,18MB): qb/kvb (used through the projection GEMMs), then reused
  // by the attention partials (written strictly after kvb/qb are dead).
  u16*   qb    = (u16*)(ws);                     // 2MB  (dead after q-proj)
  u16*   kvb   = (u16*)(ws + (2u  << 20));       // 16MB (dead after kv-proj)
  float* Mst   = (float*)(ws);                   // 256KB  (aliases qb)
  float* Lst   = (float*)(ws + (1u  << 20));     // 256KB  (aliases qb)
  float* Opart = (float*)(ws + (2u  << 20));     // 16MB   (aliases kvb)
  u16* Wqt  = (u16*)(ws + (18u << 20));          // 2MB
  u16* Wkvt = (u16*)(ws + (20u << 20));          // 4MB
  u16* Wot  = (u16*)(ws + (24u << 20));          // 2MB
  u16* qh   = (u16*)(ws + (26u << 20));          // 2MB
  u16* kvp  = (u16*)(ws + (28u << 20));          // 32MB
  u16* attn = (u16*)(ws + (60u << 20));          // 2MB -> total 62MB

  conv_bf16<<<dim3((BATCH * NQ * DMODEL) / 2048), 256, 0, stream>>>(q, qb);
  conv_bf16<<<dim3((BATCH * NKV * DMODEL) / 2048), 256, 0, stream>>>(kv, kvb);
  transpose_conv<<<dim3(INNER / 32, DMODEL / 32), 256, 0, stream>>>(Wq, Wqt, DMODEL, INNER);
  transpose_conv<<<dim3(2 * INNER / 32, DMODEL / 32), 256, 0, stream>>>(Wkv, Wkvt, DMODEL, 2 * INNER);
  transpose_conv<<<dim3(DMODEL / 32, INNER / 32), 256, 0, stream>>>(Wo, Wot, INNER, DMODEL);

  // qh = qb @ Wq   (1024x1024x1024)
  gemm_bt<true><<<dim3(INNER / 128, (BATCH * NQ) / 128), 256, 0, stream>>>(
      qb, Wqt, nullptr, qh, nullptr, BATCH * NQ, INNER, DMODEL);
  // kvp = kvb @ Wkv (8192x2048x1024)
  gemm_bt<true><<<dim3((2 * INNER) / 128, (BATCH * NKV) / 128), 256, 0, stream>>>(
      kvb, Wkvt, nullptr, kvp, nullptr, BATCH * NKV, 2 * INNER, DMODEL);
  // attention: split-K partials + combine
  attn_part<<<dim3(BATCH * HEADS * (NQ / 64) * SPLIT), 256, 0, stream>>>(
      qh, kvp, mask, Opart, Mst, Lst);
  attn_combine<<<dim3(BATCH * HEADS * (NQ / 64)), 256, 0, stream>>>(Opart, Mst, Lst, attn);
  // out = attn @ Wo + bo (fp32)
  gemm_bt<false><<<dim3(DMODEL / 128, (BATCH * NQ) / 128), 256, 0, stream>>>(
      attn, Wot, out, nullptr, bo, BATCH * NQ, DMODEL, INNER);
}